// Round 2
// baseline (265.756 us; speedup 1.0000x reference)
//
#include <hip/hip_runtime.h>

// Shapes fixed by setup_inputs():
#define BB    8
#define CF    256
#define HF    128
#define WF    128
#define HLBL  512
#define WLBL  512
#define COLD  16
#define NCLS  21
#define PSTR  260   // padded LDS stride (multiple of 4 -> 16B-aligned rows)
#define NPART (BB * HF)

// d_ws layout (partial mode): float[NPART][32] : per-block {sums[16], counts[16]}
// d_ws layout (fallback mode): float[32] atomic bins (memset first)

__global__ __launch_bounds__(256) void proto_loss_main(
    const float* __restrict__ outputs_old,   // [B, COLD, HL, WL]
    const float* __restrict__ features,      // [B, CF, HF, WF]
    const int*   __restrict__ labels,        // [B, HL, WL]
    const float* __restrict__ prototypes,    // [NCLS, CF]
    float* __restrict__ gpart,               // see layouts above
    const int nparts)
{
    // ids = argmax over COLD=16 channels -> ids in [0,16). Only 16 proto rows needed.
    __shared__ float sproto[COLD * PSTR];    // 16.25 KB
    __shared__ float spartial[8][WF];        // 4 KB
    __shared__ int   sids[WF];
    __shared__ int   sglist[WF / 4];         // active 4-pixel group list
    __shared__ int   sgcount;
    __shared__ float ssum[16];
    __shared__ float scnt[16];

    const int t   = threadIdx.x;
    const int blk = blockIdx.x;              // 0 .. B*HF-1
    const int b   = blk >> 7;                // / HF
    const int h   = blk & (HF - 1);          // % HF

    // stage prototype rows 0..15 as float4 (1024 float4 / 256 threads = 4 each)
    #pragma unroll
    for (int i = t; i < COLD * (CF / 4); i += 256) {
        const int r  = i >> 6;               // / (CF/4)
        const int c4 = (i & 63) << 2;
        *(float4*)&sproto[r * PSTR + c4] =
            *(const float4*)&prototypes[r * CF + c4];
    }
    if (t < 16) { ssum[t] = 0.0f; scnt[t] = 0.0f; }
    if (t == 0) sgcount = 0;

    // per-pixel pseudo-class ids (nearest-down: src = (4h, 4w))
    if (t < WF) {
        const int w = t;
        int id = 0;
        const int lab = labels[(b * HLBL + h * 4) * WLBL + w * 4];
        if (lab == 0) {
            const float* po = outputs_old
                + ((size_t)b * COLD * HLBL + (size_t)h * 4) * WLBL + w * 4;
            float best = po[0];
            #pragma unroll
            for (int c = 1; c < COLD; ++c) {
                float v = po[(size_t)c * HLBL * WLBL];
                if (v > best) { best = v; id = c; }   // strict >: first-max tie-break
            }
        }
        sids[w] = id;
    }
    __syncthreads();   // sproto, sids, sgcount=0 all visible

    // Build compact list of active 4-pixel groups. Class-0 bin is dropped by the
    // reference (per_class[1:]), so all-id==0 groups contribute nothing.
    if (t < WF / 4) {
        const int w4 = t * 4;
        if ((sids[w4] | sids[w4 + 1] | sids[w4 + 2] | sids[w4 + 3]) != 0) {
            const int pos = atomicAdd(&sgcount, 1);
            sglist[pos] = t;
        }
    }
    __syncthreads();

    // Phase 2 (compacted): only threads t < 8*m run the channel loop, so with
    // m ~ 5-6 active groups per row, 1 wave works while 3 skip via execz.
    // Exec-masked lanes issue no VMEM, so HBM fetch is unchanged vs full sweep.
    const int m     = sgcount;
    const int s     = t >> 3;                // group slot 0..31
    const int c_off = t & 7;                 // channel phase 0..7
    if (s < m) {
        const int g  = sglist[s];
        const int w4 = g * 4;
        const int id0 = sids[w4 + 0];
        const int id1 = sids[w4 + 1];
        const int id2 = sids[w4 + 2];
        const int id3 = sids[w4 + 3];
        const float* pr0 = &sproto[id0 * PSTR];
        const float* pr1 = &sproto[id1 * PSTR];
        const float* pr2 = &sproto[id2 * PSTR];
        const float* pr3 = &sproto[id3 * PSTR];
        const float* fbase = features + ((size_t)b * CF * HF + h) * WF + w4;

        float a0 = 0.f, a1 = 0.f, a2 = 0.f, a3 = 0.f;
        #pragma unroll 8
        for (int k = 0; k < 32; ++k) {
            const int c = k * 8 + c_off;
            const float4 f = *(const float4*)(fbase + (size_t)c * (HF * WF));
            float d0 = f.x - pr0[c]; a0 += d0 * d0;
            float d1 = f.y - pr1[c]; a1 += d1 * d1;
            float d2 = f.z - pr2[c]; a2 += d2 * d2;
            float d3 = f.w - pr3[c]; a3 += d3 * d3;
        }
        spartial[c_off][w4 + 0] = a0;
        spartial[c_off][w4 + 1] = a1;
        spartial[c_off][w4 + 2] = a2;
        spartial[c_off][w4 + 3] = a3;
    }
    __syncthreads();

    // Phase 3: per-pixel value -> per-class LDS bins (id==0 pixels skipped;
    // spartial for their groups may be stale, but is never read)
    if (t < WF) {
        const int id = sids[t];
        if (id != 0) {
            float pp = 0.f;
            #pragma unroll
            for (int co = 0; co < 8; ++co) pp += spartial[co][t];
            pp *= (1.0f / CF);
            atomicAdd(&ssum[id], pp);
            atomicAdd(&scnt[id], 1.0f);
        }
    }
    __syncthreads();

    if (t < 32) {
        const float v = (t < 16) ? ssum[t] : scnt[t - 16];
        if (nparts > 1) {
            gpart[(size_t)blk * 32 + t] = v;       // one coalesced 128B store
        } else {
            if (v != 0.f) atomicAdd(&gpart[t], v); // fallback path
        }
    }
}

__global__ __launch_bounds__(256) void proto_loss_final(
    const float* __restrict__ gpart, const int nparts,
    const int* __restrict__ classes_old,
    const int* __restrict__ inc_step,
    float* __restrict__ out)
{
    __shared__ float sacc[8][32];
    const int t     = threadIdx.x;
    const int bin   = t & 31;
    const int slice = t >> 5;

    float acc = 0.f;
    #pragma unroll 8
    for (int i = slice; i < nparts; i += 8)
        acc += gpart[(size_t)i * 32 + bin];
    sacc[slice][bin] = acc;
    __syncthreads();

    if (t < 32) {
        float v = 0.f;
        #pragma unroll
        for (int s2 = 0; s2 < 8; ++s2) v += sacc[s2][t];
        sacc[0][t] = v;
    }
    __syncthreads();

    if (t == 0) {
        float r = 0.0f;
        if (*inc_step != 0) {
            int K = *classes_old;
            if (K > 16) K = 16;
            for (int id = 1; id < K; ++id) {
                const float cnt = sacc[0][16 + id];
                if (cnt > 0.f) r += sacc[0][id] / cnt;
            }
        }
        out[0] = r;
    }
}

extern "C" void kernel_launch(void* const* d_in, const int* in_sizes, int n_in,
                              void* d_out, int out_size, void* d_ws, size_t ws_size,
                              hipStream_t stream)
{
    const float* outputs_old = (const float*)d_in[1];
    const float* features    = (const float*)d_in[2];
    const int*   labels      = (const int*)d_in[4];
    const float* prototypes  = (const float*)d_in[5];
    const int*   classes_old = (const int*)d_in[6];
    const int*   inc_step    = (const int*)d_in[7];

    float* gpart = (float*)d_ws;
    const size_t needed = (size_t)NPART * 32 * sizeof(float);   // 128 KB

    int nparts;
    if (ws_size >= needed) {
        nparts = NPART;           // partial-write mode: no memset needed
    } else {
        nparts = 1;               // fallback: zeroed atomic bins
        hipMemsetAsync(gpart, 0, 32 * sizeof(float), stream);
    }

    proto_loss_main<<<dim3(NPART), dim3(256), 0, stream>>>(
        outputs_old, features, labels, prototypes, gpart, nparts);
    proto_loss_final<<<dim3(1), dim3(256), 0, stream>>>(
        gpart, nparts, classes_old, inc_step, (float*)d_out);
}